// Round 1
// baseline (863.695 us; speedup 1.0000x reference)
//
#include <hip/hip_runtime.h>
#include <math.h>

#define HID 4096
#define NH 32
#define HD 128
#define BB 8
#define SS 8
#define MM 64              // B*S rows
#define MAXT 4096
#define QKV_N (3*HID)      // 12288
#define KSPLIT 4
#define CHUNK 1024
#define NCHUNK (MAXT/CHUNK)
#define TILE 64
#define NT 64
#define KC 32

__device__ __forceinline__ float wred_sum(float v) {
#pragma unroll
    for (int i = 1; i < 64; i <<= 1) v += __shfl_xor(v, i, 64);
    return v;
}
__device__ __forceinline__ float wred_max(float v) {
#pragma unroll
    for (int i = 1; i < 64; i <<= 1) v = fmaxf(v, __shfl_xor(v, i, 64));
    return v;
}

// -------------------- LayerNorm: 64 rows of 4096 --------------------
__global__ __launch_bounds__(256)
void ln_kernel(const float* __restrict__ tokens, const float* __restrict__ gamma,
               const float* __restrict__ beta, float* __restrict__ xout) {
    const int row = blockIdx.x;
    const float* in = tokens + (size_t)row * HID;
    float* out = xout + (size_t)row * HID;
    const int tid = threadIdx.x;
    float s = 0.f, s2 = 0.f;
    float4 vals[4];
#pragma unroll
    for (int i = 0; i < 4; ++i) {
        float4 v = *(const float4*)(in + (size_t)(i*256 + tid)*4);
        vals[i] = v;
        s  += v.x + v.y + v.z + v.w;
        s2 += v.x*v.x + v.y*v.y + v.z*v.z + v.w*v.w;
    }
    s = wred_sum(s); s2 = wred_sum(s2);
    __shared__ float red[8];
    int wid = tid >> 6, lane = tid & 63;
    if (lane == 0) { red[wid] = s; red[4+wid] = s2; }
    __syncthreads();
    s  = red[0]+red[1]+red[2]+red[3];
    s2 = red[4]+red[5]+red[6]+red[7];
    float mean = s * (1.f/HID);
    float var  = s2 * (1.f/HID) - mean*mean;
    float rstd = rsqrtf(var + 1e-5f);
#pragma unroll
    for (int i = 0; i < 4; ++i) {
        int base = (i*256 + tid)*4;
        float4 v = vals[i];
        float4 g  = *(const float4*)(gamma + base);
        float4 bt = *(const float4*)(beta + base);
        float4 o;
        o.x = (v.x - mean)*rstd*g.x + bt.x;
        o.y = (v.y - mean)*rstd*g.y + bt.y;
        o.z = (v.z - mean)*rstd*g.z + bt.z;
        o.w = (v.w - mean)*rstd*g.w + bt.w;
        *(float4*)(out + base) = o;
    }
}

// ------------- fp32 GEMM: y_part[kc][m][n] = sum_k x[m,k]*w[n,k] -------------
// x: M(=64) x K row-major, w: N x K row-major, partials over KSPLIT k-ranges.
__global__ __launch_bounds__(256)
void gemm_part(const float* __restrict__ x, const float* __restrict__ w,
               float* __restrict__ part, int N, int K) {
    __shared__ float xt[KC][MM + 4];   // [k][m], stride 68 keeps 16B align + spreads banks
    __shared__ float wt[KC][NT + 4];   // [k][n]
    const int n0 = blockIdx.x * NT;
    const int kc = blockIdx.y;
    const int kLen = K / KSPLIT;
    const int kBeg = kc * kLen;
    const int tid = threadIdx.x;
    const int mg = tid >> 4;           // 0..15 -> m = mg*4
    const int ng = tid & 15;           // 0..15 -> n = ng*4
    const int lr = tid >> 2;           // staging row 0..63
    const int lk = (tid & 3) * 8;      // staging k offset
    float acc[4][4] = {{0.f}};
    const float* xsrc = x + (size_t)lr * K + kBeg + lk;
    const float* wsrc = w + (size_t)(n0 + lr) * K + kBeg + lk;
    for (int kk = 0; kk < kLen; kk += KC) {
        float4 a0 = *(const float4*)(xsrc + kk);
        float4 a1 = *(const float4*)(xsrc + kk + 4);
        float4 b0 = *(const float4*)(wsrc + kk);
        float4 b1 = *(const float4*)(wsrc + kk + 4);
        __syncthreads();
        xt[lk+0][lr]=a0.x; xt[lk+1][lr]=a0.y; xt[lk+2][lr]=a0.z; xt[lk+3][lr]=a0.w;
        xt[lk+4][lr]=a1.x; xt[lk+5][lr]=a1.y; xt[lk+6][lr]=a1.z; xt[lk+7][lr]=a1.w;
        wt[lk+0][lr]=b0.x; wt[lk+1][lr]=b0.y; wt[lk+2][lr]=b0.z; wt[lk+3][lr]=b0.w;
        wt[lk+4][lr]=b1.x; wt[lk+5][lr]=b1.y; wt[lk+6][lr]=b1.z; wt[lk+7][lr]=b1.w;
        __syncthreads();
#pragma unroll
        for (int k = 0; k < KC; ++k) {
            float4 xv = *(const float4*)&xt[k][mg*4];
            float4 wv = *(const float4*)&wt[k][ng*4];
            acc[0][0] += xv.x*wv.x; acc[0][1] += xv.x*wv.y; acc[0][2] += xv.x*wv.z; acc[0][3] += xv.x*wv.w;
            acc[1][0] += xv.y*wv.x; acc[1][1] += xv.y*wv.y; acc[1][2] += xv.y*wv.z; acc[1][3] += xv.y*wv.w;
            acc[2][0] += xv.z*wv.x; acc[2][1] += xv.z*wv.y; acc[2][2] += xv.z*wv.z; acc[2][3] += xv.z*wv.w;
            acc[3][0] += xv.w*wv.x; acc[3][1] += xv.w*wv.y; acc[3][2] += xv.w*wv.z; acc[3][3] += xv.w*wv.w;
        }
    }
    float* dst = part + (size_t)kc * MM * N + (size_t)(mg*4) * N + n0 + ng*4;
#pragma unroll
    for (int i = 0; i < 4; ++i) {
        float4 o = make_float4(acc[i][0], acc[i][1], acc[i][2], acc[i][3]);
        *(float4*)(dst + (size_t)i * N) = o;
    }
}

// ---------------- sum KSPLIT partials + bias ----------------
__global__ __launch_bounds__(256)
void combine_bias(const float* __restrict__ part, const float* __restrict__ bias,
                  float* __restrict__ out, int N, int totalv4) {
    int idx = blockIdx.x * 256 + threadIdx.x;
    if (idx >= totalv4) return;
    size_t base = (size_t)idx * 4;
    size_t MN = (size_t)MM * N;
    float4 a = *(const float4*)(part + base);
    float4 b = *(const float4*)(part + MN + base);
    float4 c = *(const float4*)(part + 2*MN + base);
    float4 d = *(const float4*)(part + 3*MN + base);
    int n = (int)(base % (size_t)N);
    float4 bb = *(const float4*)(bias + n);
    float4 o;
    o.x = a.x+b.x+c.x+d.x+bb.x;
    o.y = a.y+b.y+c.y+d.y+bb.y;
    o.z = a.z+b.z+c.z+d.z+bb.z;
    o.w = a.w+b.w+c.w+d.w+bb.w;
    *(float4*)(out + base) = o;
}

// ---------------- attention partial: one (b,h) x one T-chunk ----------------
// Online softmax over the chunk; writes acc[8][128], m[8], l[8] partials.
__global__ __launch_bounds__(256)
void attn_part(const float* __restrict__ qkv, const float* __restrict__ cache_k,
               const float* __restrict__ cache_v, const int* __restrict__ d_start,
               float* __restrict__ accp, float* __restrict__ mlp) {
    __shared__ float q_lds[SS*HD];
    __shared__ float k_lds[TILE*HD];
    __shared__ float v_lds[TILE*HD];
    __shared__ float p_lds[SS*TILE];
    __shared__ float alpha_lds[SS];
    const int bh = blockIdx.x;
    const int b = bh >> 5, h = bh & 31;
    const int c = blockIdx.y;
    const int tid = threadIdx.x;
    const int start = d_start[0];
    const int T = start + SS;
    const float scale = 0.08838834764831845f;   // 1/sqrt(128)

    {   // load q tile (8 x 128)
        int s = tid >> 5, dg = tid & 31;
        *(float4*)&q_lds[s*HD + dg*4] =
            *(const float4*)(qkv + (size_t)(b*SS + s)*QKV_N + h*HD + dg*4);
    }
    // score-phase mapping: lane owns one t, wave owns an s-pair
    const int ts = tid & 63;
    const int sg = tid >> 6;
    const int s0 = sg*2, s1 = s0+1;
    // pv-phase mapping: thread owns (s, 4-wide d slice)
    const int sv = tid >> 5;
    const int dgv = tid & 31;
    // staging mapping: 4 threads per row, 8 float4-slots each
    const int sr = tid >> 2;
    const int ss0 = (tid & 3) * 8;

    float m0 = -1e30f, m1 = -1e30f, l0 = 0.f, l1 = 0.f;
    float4 oacc = make_float4(0.f,0.f,0.f,0.f);

    for (int tile = 0; tile < CHUNK/TILE; ++tile) {
        const int tbase = c*CHUNK + tile*TILE;
        __syncthreads();   // protect k/v/p_lds from previous iteration readers
        {   // stage K,V rows (XOR-swizzled 16B slots: slot' = slot ^ (row&7))
            int tg = tbase + sr;
            const float* srck; const float* srcv;
            bool valid = tg < T;
            if (tg >= start && tg < T) {
                size_t rowo = (size_t)(b*SS + (tg - start)) * QKV_N + h*HD;
                srck = qkv + rowo + HID;
                srcv = qkv + rowo + 2*HID;
            } else {
                size_t rowo = (((size_t)b*MAXT + tg)*NH + h) * (size_t)HD;
                srck = cache_k + rowo;
                srcv = cache_v + rowo;
            }
#pragma unroll
            for (int j = 0; j < 8; ++j) {
                int slot = ss0 + j;
                int off = sr*HD + (((slot ^ (sr & 7)) << 2));
                float4 kv = valid ? *(const float4*)(srck + slot*4) : make_float4(0.f,0.f,0.f,0.f);
                float4 vv = valid ? *(const float4*)(srcv + slot*4) : make_float4(0.f,0.f,0.f,0.f);
                *(float4*)&k_lds[off] = kv;
                *(float4*)&v_lds[off] = vv;
            }
        }
        __syncthreads();
        {   // scores + online softmax state
            float d0 = 0.f, d1 = 0.f;
#pragma unroll
            for (int dg = 0; dg < 32; ++dg) {
                float4 kv = *(const float4*)&k_lds[ts*HD + (((dg ^ (ts & 7)) << 2))];
                float4 qa = *(const float4*)&q_lds[s0*HD + dg*4];
                float4 qb = *(const float4*)&q_lds[s1*HD + dg*4];
                d0 += kv.x*qa.x + kv.y*qa.y + kv.z*qa.z + kv.w*qa.w;
                d1 += kv.x*qb.x + kv.y*qb.y + kv.z*qb.z + kv.w*qb.w;
            }
            int tg = tbase + ts;
            float sc0 = (tg < T) ? d0 * scale : -1e30f;
            float sc1 = (tg < T) ? d1 * scale : -1e30f;
            float mt0 = wred_max(sc0), mt1 = wred_max(sc1);
            float mn0 = fmaxf(m0, mt0), mn1 = fmaxf(m1, mt1);
            float a0 = __expf(m0 - mn0), a1 = __expf(m1 - mn1);
            float p0 = (tg < T) ? __expf(sc0 - mn0) : 0.f;
            float p1 = (tg < T) ? __expf(sc1 - mn1) : 0.f;
            l0 = l0 * a0 + wred_sum(p0);
            l1 = l1 * a1 + wred_sum(p1);
            m0 = mn0; m1 = mn1;
            p_lds[s0*TILE + ts] = p0;
            p_lds[s1*TILE + ts] = p1;
            if (ts == 0) { alpha_lds[s0] = a0; alpha_lds[s1] = a1; }
        }
        __syncthreads();
        {   // PV accumulate with rescale
            float al = alpha_lds[sv];
            oacc.x *= al; oacc.y *= al; oacc.z *= al; oacc.w *= al;
#pragma unroll
            for (int t2 = 0; t2 < TILE; ++t2) {
                float pp = p_lds[sv*TILE + t2];
                float4 vv = *(const float4*)&v_lds[t2*HD + (((dgv ^ (t2 & 7)) << 2))];
                oacc.x += pp*vv.x; oacc.y += pp*vv.y; oacc.z += pp*vv.z; oacc.w += pp*vv.w;
            }
        }
    }
    size_t pbase = ((size_t)(bh*NCHUNK + c) * SS + sv) * HD + dgv*4;
    *(float4*)(accp + pbase) = oacc;
    if (ts == 0) {
        size_t mb = (size_t)(bh*NCHUNK + c) * 16;
        mlp[mb + s0] = m0;      mlp[mb + s1] = m1;
        mlp[mb + 8 + s0] = l0;  mlp[mb + 8 + s1] = l1;
    }
}

// ---------------- combine chunk partials -> attn_out (64 x 4096) ----------------
__global__ __launch_bounds__(256)
void attn_combine(const float* __restrict__ accp, const float* __restrict__ mlp,
                  float* __restrict__ attn_out) {
    const int bh = blockIdx.x;
    const int b = bh >> 5, h = bh & 31;
    const int tid = threadIdx.x;
    const int s = tid >> 5, dg = tid & 31;
    float mC[NCHUNK], lC[NCHUNK];
    float M = -1e30f;
#pragma unroll
    for (int c = 0; c < NCHUNK; ++c) {
        size_t mb = (size_t)(bh*NCHUNK + c) * 16;
        mC[c] = mlp[mb + s];
        lC[c] = mlp[mb + 8 + s];
        M = fmaxf(M, mC[c]);
    }
    float L = 0.f;
    float4 o = make_float4(0.f,0.f,0.f,0.f);
#pragma unroll
    for (int c = 0; c < NCHUNK; ++c) {
        float wgt = __expf(mC[c] - M);
        L += wgt * lC[c];
        float4 a = *(const float4*)(accp + ((size_t)(bh*NCHUNK + c) * SS + s) * HD + dg*4);
        o.x += wgt*a.x; o.y += wgt*a.y; o.z += wgt*a.z; o.w += wgt*a.w;
    }
    float inv = 1.f / L;
    o.x *= inv; o.y *= inv; o.z *= inv; o.w *= inv;
    *(float4*)(attn_out + (size_t)(b*SS + s)*HID + h*HD + dg*4) = o;
}

extern "C" void kernel_launch(void* const* d_in, const int* in_sizes, int n_in,
                              void* d_out, int out_size, void* d_ws, size_t ws_size,
                              hipStream_t stream) {
    const float* tokens  = (const float*)d_in[0];
    const float* cache_k = (const float*)d_in[1];
    const float* cache_v = (const float*)d_in[2];
    const float* gamma   = (const float*)d_in[3];
    const float* beta    = (const float*)d_in[4];
    const float* qkv_w   = (const float*)d_in[5];
    const float* qkv_b   = (const float*)d_in[6];
    const float* proj_w  = (const float*)d_in[7];
    const float* proj_b  = (const float*)d_in[8];
    const int*   d_start = (const int*)d_in[9];
    float* out = (float*)d_out;
    char* ws = (char*)d_ws;

    // workspace layout (bytes): [0,1M) x_ln | [1M,4M) qkv | [4M,16M) gemm partials
    // (reused: [4M,8M) attn acc partials, [8M,8M+64K) m/l, then proj partials) | [16M,17M) attn_out
    float* x_ln     = (float*)ws;
    float* qkv      = (float*)(ws + (1u<<20));
    float* part     = (float*)(ws + (4u<<20));
    float* accp     = (float*)(ws + (4u<<20));
    float* mlp      = (float*)(ws + (8u<<20));
    float* attn_out = (float*)(ws + (16u<<20));

    ln_kernel<<<MM, 256, 0, stream>>>(tokens, gamma, beta, x_ln);
    gemm_part<<<dim3(QKV_N/NT, KSPLIT), 256, 0, stream>>>(x_ln, qkv_w, part, QKV_N, HID);
    combine_bias<<<(MM*QKV_N/4 + 255)/256, 256, 0, stream>>>(part, qkv_b, qkv, QKV_N, MM*QKV_N/4);
    attn_part<<<dim3(BB*NH, NCHUNK), 256, 0, stream>>>(qkv, cache_k, cache_v, d_start, accp, mlp);
    attn_combine<<<BB*NH, 256, 0, stream>>>(accp, mlp, attn_out);
    gemm_part<<<dim3(HID/NT, KSPLIT), 256, 0, stream>>>(attn_out, proj_w, part, HID, HID);
    combine_bias<<<(MM*HID/4 + 255)/256, 256, 0, stream>>>(part, proj_b, out, HID, MM*HID/4);
}

// Round 2
// 650.925 us; speedup vs baseline: 1.3269x; 1.3269x over previous
//
#include <hip/hip_runtime.h>
#include <math.h>

#define HID 4096
#define NH 32
#define HD 128
#define BB 8
#define SS 8
#define MM 64              // B*S rows
#define MAXT 4096
#define QKV_N (3*HID)      // 12288
#define KSPLIT 4
#define CHUNK 1024
#define NCHUNK (MAXT/CHUNK)
#define TILE 64
#define NT 64
#define KC 32

__device__ __forceinline__ float wred_sum(float v) {
#pragma unroll
    for (int i = 1; i < 64; i <<= 1) v += __shfl_xor(v, i, 64);
    return v;
}
__device__ __forceinline__ float wred_max(float v) {
#pragma unroll
    for (int i = 1; i < 64; i <<= 1) v = fmaxf(v, __shfl_xor(v, i, 64));
    return v;
}

// -------------------- LayerNorm: 64 rows of 4096 --------------------
__global__ __launch_bounds__(256)
void ln_kernel(const float* __restrict__ tokens, const float* __restrict__ gamma,
               const float* __restrict__ beta, float* __restrict__ xout) {
    const int row = blockIdx.x;
    const float* in = tokens + (size_t)row * HID;
    float* out = xout + (size_t)row * HID;
    const int tid = threadIdx.x;
    float s = 0.f, s2 = 0.f;
    float4 vals[4];
#pragma unroll
    for (int i = 0; i < 4; ++i) {
        float4 v = *(const float4*)(in + (size_t)(i*256 + tid)*4);
        vals[i] = v;
        s  += v.x + v.y + v.z + v.w;
        s2 += v.x*v.x + v.y*v.y + v.z*v.z + v.w*v.w;
    }
    s = wred_sum(s); s2 = wred_sum(s2);
    __shared__ float red[8];
    int wid = tid >> 6, lane = tid & 63;
    if (lane == 0) { red[wid] = s; red[4+wid] = s2; }
    __syncthreads();
    s  = red[0]+red[1]+red[2]+red[3];
    s2 = red[4]+red[5]+red[6]+red[7];
    float mean = s * (1.f/HID);
    float var  = s2 * (1.f/HID) - mean*mean;
    float rstd = rsqrtf(var + 1e-5f);
#pragma unroll
    for (int i = 0; i < 4; ++i) {
        int base = (i*256 + tid)*4;
        float4 v = vals[i];
        float4 g  = *(const float4*)(gamma + base);
        float4 bt = *(const float4*)(beta + base);
        float4 o;
        o.x = (v.x - mean)*rstd*g.x + bt.x;
        o.y = (v.y - mean)*rstd*g.y + bt.y;
        o.z = (v.z - mean)*rstd*g.z + bt.z;
        o.w = (v.w - mean)*rstd*g.w + bt.w;
        *(float4*)(out + base) = o;
    }
}

// ------------- fp32 GEMM: y_part[kc][m][n] = sum_k x[m,k]*w[n,k] -------------
__global__ __launch_bounds__(256)
void gemm_part(const float* __restrict__ x, const float* __restrict__ w,
               float* __restrict__ part, int N, int K) {
    __shared__ float xt[KC][MM + 4];
    __shared__ float wt[KC][NT + 4];
    const int n0 = blockIdx.x * NT;
    const int kc = blockIdx.y;
    const int kLen = K / KSPLIT;
    const int kBeg = kc * kLen;
    const int tid = threadIdx.x;
    const int mg = tid >> 4;
    const int ng = tid & 15;
    const int lr = tid >> 2;
    const int lk = (tid & 3) * 8;
    float acc[4][4] = {{0.f}};
    const float* xsrc = x + (size_t)lr * K + kBeg + lk;
    const float* wsrc = w + (size_t)(n0 + lr) * K + kBeg + lk;
    for (int kk = 0; kk < kLen; kk += KC) {
        float4 a0 = *(const float4*)(xsrc + kk);
        float4 a1 = *(const float4*)(xsrc + kk + 4);
        float4 b0 = *(const float4*)(wsrc + kk);
        float4 b1 = *(const float4*)(wsrc + kk + 4);
        __syncthreads();
        xt[lk+0][lr]=a0.x; xt[lk+1][lr]=a0.y; xt[lk+2][lr]=a0.z; xt[lk+3][lr]=a0.w;
        xt[lk+4][lr]=a1.x; xt[lk+5][lr]=a1.y; xt[lk+6][lr]=a1.z; xt[lk+7][lr]=a1.w;
        wt[lk+0][lr]=b0.x; wt[lk+1][lr]=b0.y; wt[lk+2][lr]=b0.z; wt[lk+3][lr]=b0.w;
        wt[lk+4][lr]=b1.x; wt[lk+5][lr]=b1.y; wt[lk+6][lr]=b1.z; wt[lk+7][lr]=b1.w;
        __syncthreads();
#pragma unroll
        for (int k = 0; k < KC; ++k) {
            float4 xv = *(const float4*)&xt[k][mg*4];
            float4 wv = *(const float4*)&wt[k][ng*4];
            acc[0][0] += xv.x*wv.x; acc[0][1] += xv.x*wv.y; acc[0][2] += xv.x*wv.z; acc[0][3] += xv.x*wv.w;
            acc[1][0] += xv.y*wv.x; acc[1][1] += xv.y*wv.y; acc[1][2] += xv.y*wv.z; acc[1][3] += xv.y*wv.w;
            acc[2][0] += xv.z*wv.x; acc[2][1] += xv.z*wv.y; acc[2][2] += xv.z*wv.z; acc[2][3] += xv.z*wv.w;
            acc[3][0] += xv.w*wv.x; acc[3][1] += xv.w*wv.y; acc[3][2] += xv.w*wv.z; acc[3][3] += xv.w*wv.w;
        }
    }
    float* dst = part + (size_t)kc * MM * N + (size_t)(mg*4) * N + n0 + ng*4;
#pragma unroll
    for (int i = 0; i < 4; ++i) {
        float4 o = make_float4(acc[i][0], acc[i][1], acc[i][2], acc[i][3]);
        *(float4*)(dst + (size_t)i * N) = o;
    }
}

// ---------------- sum KSPLIT partials + bias ----------------
__global__ __launch_bounds__(256)
void combine_bias(const float* __restrict__ part, const float* __restrict__ bias,
                  float* __restrict__ out, int N, int totalv4) {
    int idx = blockIdx.x * 256 + threadIdx.x;
    if (idx >= totalv4) return;
    size_t base = (size_t)idx * 4;
    size_t MN = (size_t)MM * N;
    float4 a = *(const float4*)(part + base);
    float4 b = *(const float4*)(part + MN + base);
    float4 c = *(const float4*)(part + 2*MN + base);
    float4 d = *(const float4*)(part + 3*MN + base);
    int n = (int)(base % (size_t)N);
    float4 bb = *(const float4*)(bias + n);
    float4 o;
    o.x = a.x+b.x+c.x+d.x+bb.x;
    o.y = a.y+b.y+c.y+d.y+bb.y;
    o.z = a.z+b.z+c.z+d.z+bb.z;
    o.w = a.w+b.w+c.w+d.w+bb.w;
    *(float4*)(out + base) = o;
}

// ---------------- attention partial: one (b,h) x one T-chunk ----------------
// K staged in LDS (swizzled, reg-prefetched); V read direct from global
// (coalesced, zero reuse); p and alpha are intra-wave. 2 barriers/tile.
__global__ __launch_bounds__(256, 4)
void attn_part(const float* __restrict__ qkv, const float* __restrict__ cache_k,
               const float* __restrict__ cache_v, const int* __restrict__ d_start,
               float* __restrict__ accp, float* __restrict__ mlp) {
    __shared__ float k_lds[TILE*HD];   // 32KB
    __shared__ float q_lds[SS*HD];     // 4KB
    __shared__ float p_lds[SS*TILE];   // 2KB
    const int bh = blockIdx.x;
    const int b = bh >> 5, h = bh & 31;
    const int c = blockIdx.y;
    const int tid = threadIdx.x;
    const int start = d_start[0];
    const int T = start + SS;
    const float scale = 0.08838834764831845f;   // 1/sqrt(128)

    {   // load q tile (8 x 128)
        int s = tid >> 5, dg = tid & 31;
        *(float4*)&q_lds[s*HD + dg*4] =
            *(const float4*)(qkv + (size_t)(b*SS + s)*QKV_N + h*HD + dg*4);
    }
    const int ts = tid & 63;           // score: lane owns t row
    const int s0 = (tid >> 6)*2, s1 = s0 + 1;
    const int sv = tid >> 5;           // PV: thread owns (s, d-slice)
    const int dgv = tid & 31;
    const int sr = tid >> 2;           // staging: 4 lanes per row
    const int sq = tid & 3;            // 128B contiguous chunk per lane

    float m0 = -1e30f, m1 = -1e30f, l0 = 0.f, l1 = 0.f;
    float4 oacc = make_float4(0.f,0.f,0.f,0.f);
    float4 kpre[8];

    // K row source: fresh rows come from qkv buffer, others from cache
    const size_t cacheRowBase = ((size_t)b*MAXT*NH + h) * (size_t)HD;

#define KROW(tg) ((tg) >= start ? (qkv + (size_t)(b*SS + ((tg)-start))*QKV_N + h*HD + HID) \
                                : (cache_k + cacheRowBase + (size_t)(tg)*NH*HD))
#define VROW(tg) ((tg) >= start ? (qkv + (size_t)(b*SS + ((tg)-start))*QKV_N + h*HD + 2*HID) \
                                : (cache_v + cacheRowBase + (size_t)(tg)*NH*HD))

    {   // prefetch tile 0
        int tg = c*CHUNK + sr;
        const float* src = KROW(tg);
#pragma unroll
        for (int j = 0; j < 8; ++j) kpre[j] = *(const float4*)(src + (sq*8+j)*4);
    }

    for (int tile = 0; tile < CHUNK/TILE; ++tile) {
        const int tbase = c*CHUNK + tile*TILE;
        __syncthreads();   // previous tile's k_lds readers done
        {   // write prefetched K (swizzle: slot ^ (row&7) ^ ((slot>>3)<<1))
#pragma unroll
            for (int j = 0; j < 8; ++j) {
                int slot = sq*8 + j;
                int swz = slot ^ (sr & 7) ^ ((slot >> 3) << 1);
                *(float4*)&k_lds[sr*HD + swz*4] = kpre[j];
            }
        }
        __syncthreads();   // k_lds ready
        if (tile + 1 < CHUNK/TILE) {   // prefetch next tile (hides HBM latency)
            int tg = tbase + TILE + sr;
            const float* src = KROW(tg);
#pragma unroll
            for (int j = 0; j < 8; ++j) kpre[j] = *(const float4*)(src + (sq*8+j)*4);
        }
        // ---- scores + online softmax (intra-wave) ----
        float d0 = 0.f, d1 = 0.f;
        const int tmask = ts & 7;
#pragma unroll
        for (int dg = 0; dg < 32; ++dg) {
            int swz = (dg ^ ((dg >> 3) << 1)) ^ tmask;
            float4 kv = *(const float4*)&k_lds[ts*HD + swz*4];
            float4 qa = *(const float4*)&q_lds[s0*HD + dg*4];
            float4 qb = *(const float4*)&q_lds[s1*HD + dg*4];
            d0 += kv.x*qa.x + kv.y*qa.y + kv.z*qa.z + kv.w*qa.w;
            d1 += kv.x*qb.x + kv.y*qb.y + kv.z*qb.z + kv.w*qb.w;
        }
        int tg = tbase + ts;
        float sc0 = (tg < T) ? d0 * scale : -1e30f;
        float sc1 = (tg < T) ? d1 * scale : -1e30f;
        float mt0 = wred_max(sc0), mt1 = wred_max(sc1);
        float mn0 = fmaxf(m0, mt0), mn1 = fmaxf(m1, mt1);
        float a0 = __expf(m0 - mn0), a1 = __expf(m1 - mn1);
        float p0 = (tg < T) ? __expf(sc0 - mn0) : 0.f;
        float p1 = (tg < T) ? __expf(sc1 - mn1) : 0.f;
        l0 = l0 * a0 + wred_sum(p0);
        l1 = l1 * a1 + wred_sum(p1);
        m0 = mn0; m1 = mn1;
        p_lds[s0*TILE + ts] = p0;
        p_lds[s1*TILE + ts] = p1;
        // p rows 2w,2w+1 are written & read only by wave w: no barrier needed.
        // ---- PV: V direct from global (all lanes same row -> coalesced) ----
        float al = (tid & 32) ? a1 : a0;
        oacc.x *= al; oacc.y *= al; oacc.z *= al; oacc.w *= al;
#pragma unroll 8
        for (int t2 = 0; t2 < TILE; ++t2) {
            int tg2 = tbase + t2;
            const float* vrow = VROW(tg2);
            float4 vv = *(const float4*)(vrow + dgv*4);
            float pp = p_lds[sv*TILE + t2];
            oacc.x += pp*vv.x; oacc.y += pp*vv.y; oacc.z += pp*vv.z; oacc.w += pp*vv.w;
        }
    }
    size_t pbase = ((size_t)(bh*NCHUNK + c) * SS + sv) * HD + dgv*4;
    *(float4*)(accp + pbase) = oacc;
    if (ts == 0) {
        size_t mb = (size_t)(bh*NCHUNK + c) * 16;
        mlp[mb + s0] = m0;      mlp[mb + s1] = m1;
        mlp[mb + 8 + s0] = l0;  mlp[mb + 8 + s1] = l1;
    }
#undef KROW
#undef VROW
}

// ---------------- combine chunk partials -> attn_out (64 x 4096) ----------------
__global__ __launch_bounds__(256)
void attn_combine(const float* __restrict__ accp, const float* __restrict__ mlp,
                  float* __restrict__ attn_out) {
    const int bh = blockIdx.x;
    const int b = bh >> 5, h = bh & 31;
    const int tid = threadIdx.x;
    const int s = tid >> 5, dg = tid & 31;
    float mC[NCHUNK], lC[NCHUNK];
    float M = -1e30f;
#pragma unroll
    for (int c = 0; c < NCHUNK; ++c) {
        size_t mb = (size_t)(bh*NCHUNK + c) * 16;
        mC[c] = mlp[mb + s];
        lC[c] = mlp[mb + 8 + s];
        M = fmaxf(M, mC[c]);
    }
    float L = 0.f;
    float4 o = make_float4(0.f,0.f,0.f,0.f);
#pragma unroll
    for (int c = 0; c < NCHUNK; ++c) {
        float wgt = __expf(mC[c] - M);
        L += wgt * lC[c];
        float4 a = *(const float4*)(accp + ((size_t)(bh*NCHUNK + c) * SS + s) * HD + dg*4);
        o.x += wgt*a.x; o.y += wgt*a.y; o.z += wgt*a.z; o.w += wgt*a.w;
    }
    float inv = 1.f / L;
    o.x *= inv; o.y *= inv; o.z *= inv; o.w *= inv;
    *(float4*)(attn_out + (size_t)(b*SS + s)*HID + h*HD + dg*4) = o;
}

extern "C" void kernel_launch(void* const* d_in, const int* in_sizes, int n_in,
                              void* d_out, int out_size, void* d_ws, size_t ws_size,
                              hipStream_t stream) {
    const float* tokens  = (const float*)d_in[0];
    const float* cache_k = (const float*)d_in[1];
    const float* cache_v = (const float*)d_in[2];
    const float* gamma   = (const float*)d_in[3];
    const float* beta    = (const float*)d_in[4];
    const float* qkv_w   = (const float*)d_in[5];
    const float* qkv_b   = (const float*)d_in[6];
    const float* proj_w  = (const float*)d_in[7];
    const float* proj_b  = (const float*)d_in[8];
    const int*   d_start = (const int*)d_in[9];
    float* out = (float*)d_out;
    char* ws = (char*)d_ws;

    float* x_ln     = (float*)ws;
    float* qkv      = (float*)(ws + (1u<<20));
    float* part     = (float*)(ws + (4u<<20));
    float* accp     = (float*)(ws + (4u<<20));
    float* mlp      = (float*)(ws + (8u<<20));
    float* attn_out = (float*)(ws + (16u<<20));

    ln_kernel<<<MM, 256, 0, stream>>>(tokens, gamma, beta, x_ln);
    gemm_part<<<dim3(QKV_N/NT, KSPLIT), 256, 0, stream>>>(x_ln, qkv_w, part, QKV_N, HID);
    combine_bias<<<(MM*QKV_N/4 + 255)/256, 256, 0, stream>>>(part, qkv_b, qkv, QKV_N, MM*QKV_N/4);
    attn_part<<<dim3(BB*NH, NCHUNK), 256, 0, stream>>>(qkv, cache_k, cache_v, d_start, accp, mlp);
    attn_combine<<<BB*NH, 256, 0, stream>>>(accp, mlp, attn_out);
    gemm_part<<<dim3(HID/NT, KSPLIT), 256, 0, stream>>>(attn_out, proj_w, part, HID, HID);
    combine_bias<<<(MM*HID/4 + 255)/256, 256, 0, stream>>>(part, proj_b, out, HID, MM*HID/4);
}